// Round 1
// 89.979 us; speedup vs baseline: 1.4856x; 1.4856x over previous
//
#include <hip/hip_runtime.h>
#include <stdint.h>

typedef __bf16 bf16x8 __attribute__((ext_vector_type(8)));
typedef float f32x4 __attribute__((ext_vector_type(4)));

#define TOK 49
#define CDIM 192
#define NHEAD 6
#define THREADS 768
#define QKSCALE 0.17677669529663687f

// LDS layout (bytes). All tiles bf16.
// x:       [64][192] stride 384B, swzA          @ 0       (24576)
// q:       6 x [64][32] stride 64B, swzQ        @ 24576   (24576)  (scale baked into packed Wq)
// k:       6 x [64][32] stride 64B, swzQ        @ 49152   (24576)
// vT:      6 x [48][64] stride 128B, swzA       @ 73728   (36864)  (rows 0-31 = v^T, row 32 = 1.0 sum col, 33-47 = 0)
// P:       12 x [16][64] stride 128B, swzA      @ 110592  (24576)  (per-wave unnormalized exp(S))
// attn_o:  [64][192] stride 384B, swzA          @ 135168  (24576)
#define XOFF   0u
#define QOFF   24576u
#define KOFF   49152u
#define VOFF   73728u
#define POFF   110592u
#define AOFF   135168u
#define SMEM_BYTES 159744u

__device__ __forceinline__ unsigned short f2bf(float f) {
  unsigned u = __float_as_uint(f);
  return (unsigned short)((u + 0x7fffu + ((u >> 16) & 1u)) >> 16);  // RNE
}
// XOR-swizzle byte-in-row for stride%128==0 tiles (bits 4-6)
__device__ __forceinline__ uint32_t swzA(uint32_t row, uint32_t b) { return b ^ ((row & 7u) << 4); }
// XOR-swizzle for stride-64B tiles (bits 4-5)
__device__ __forceinline__ uint32_t swzQ(uint32_t row, uint32_t b) { return b ^ (((row >> 1) & 3u) << 4); }

// Pack fp32 weight matrix [192][NT*16] row-major into bf16 MFMA B-fragments:
// frag (nt, ks): lane l gets B[ks*32 + (l>>4)*8 + j][nt*16 + (l&15)], j=0..7, stored
// contiguously at ((nt*6+ks)*64 + l)*8 bf16. Columns nt < nscale are pre-multiplied by scale.
__global__ void wa_pack_w(const float* __restrict__ w, unsigned short* __restrict__ outp,
                          int NT, int ncols, int nscale, float scale) {
  int idx = blockIdx.x * blockDim.x + threadIdx.x;
  if (idx >= NT * 6 * 64) return;
  int l = idx & 63;
  int frag = idx >> 6;
  int ks = frag % 6;
  int nt = frag / 6;
  float sc = (nt < nscale) ? scale : 1.0f;
  int n = nt * 16 + (l & 15);
  int k0 = ks * 32 + ((l >> 4) << 3);
  unsigned short v[8];
#pragma unroll
  for (int j = 0; j < 8; ++j) v[j] = f2bf(w[(k0 + j) * ncols + n] * sc);
  ushort4* dst = reinterpret_cast<ushort4*>(outp + (size_t)idx * 8);
  dst[0] = make_ushort4(v[0], v[1], v[2], v[3]);
  dst[1] = make_ushort4(v[4], v[5], v[6], v[7]);
}

// Precompute relative-position bias in MFMA C-fragment layout:
// out[((head*4 + mtile)*4 + nt)*64 + lane][r] = bias(row=mtile*16+(lane>>4)*4+r, col=nt*16+(lane&15))
// with -1e30 for masked (row>=49 || col>=49) entries so softmax masking is free.
__global__ void wa_pack_bias(const float* __restrict__ rpb, float* __restrict__ outb) {
  int idx = blockIdx.x * blockDim.x + threadIdx.x;
  if (idx >= NHEAD * 4 * 4 * 64) return;
  int lane = idx & 63;
  int nt = (idx >> 6) & 3;
  int mtile = (idx >> 8) & 3;
  int head = idx >> 10;
  int col = nt * 16 + (lane & 15);
  int row0 = mtile * 16 + ((lane >> 4) << 2);
  float4 v;
  float* vp = reinterpret_cast<float*>(&v);
#pragma unroll
  for (int r = 0; r < 4; ++r) {
    int row = row0 + r;
    float val = -1e30f;
    if (row < TOK && col < TOK) {
      int ri = (row / 7 - col / 7 + 6) * 13 + (row % 7 - col % 7 + 6);
      val = rpb[ri * NHEAD + head];
    }
    vp[r] = val;
  }
  *reinterpret_cast<float4*>(outb + (size_t)idx * 4) = v;
}

__global__ __launch_bounds__(THREADS) void wa_main(
    const float* __restrict__ x,
    const float* __restrict__ qkv_b,
    const float* __restrict__ proj_b,
    const float* __restrict__ bias_c,          // C-fragment-layout bias table
    const unsigned short* __restrict__ wqkv,   // packed 36 ntiles (q cols pre-scaled)
    const unsigned short* __restrict__ wproj,  // packed 12 ntiles
    float* __restrict__ out) {
  extern __shared__ __align__(16) char smem[];
  const int tid = threadIdx.x;
  const int wave = tid >> 6;
  const int lane = tid & 63;
  const int l15 = lane & 15;
  const int g16 = (lane >> 4) << 4;   // byte offset of this lane-group's 16B k-slice
  const int rloc0 = (lane >> 4) << 2;
  const int b = blockIdx.x;
  const float* xg = x + (size_t)b * (TOK * CDIM);

  // ---- Phase 1: x -> LDS bf16 [64][192] (rows 49..63 zero); vT pad rows fill ----
  for (int c = tid; c < 64 * 48; c += THREADS) {
    int r = c / 48;
    int cc = (c % 48) * 4;
    uint32_t addr = XOFF + (uint32_t)r * 384u + swzA((uint32_t)r, (uint32_t)(cc * 2));
    ushort4 hv;
    if (r < TOK) {
      const float4 v = *reinterpret_cast<const float4*>(xg + r * CDIM + cc);
      hv = make_ushort4(f2bf(v.x), f2bf(v.y), f2bf(v.z), f2bf(v.w));
    } else {
      hv = make_ushort4(0, 0, 0, 0);
    }
    *reinterpret_cast<ushort4*>(smem + addr) = hv;
  }
  {
    // vT rows 32..47 per head: row 32 = bf16(1.0) (sum column), rows 33..47 = 0.
    // 6 heads * 16 rows * 128B = 12288B = 768 * 16B -> exactly one uint4 store per thread.
    int head = tid >> 7;
    int loc = tid & 127;
    uint32_t addr = VOFF + (uint32_t)head * 6144u + 4096u + (uint32_t)loc * 16u;
    uint4 fill = (loc < 8) ? make_uint4(0x3F803F80u, 0x3F803F80u, 0x3F803F80u, 0x3F803F80u)
                           : make_uint4(0u, 0u, 0u, 0u);
    *reinterpret_cast<uint4*>(smem + addr) = fill;
  }
  __syncthreads();

  // ---- Phase 2: qkv GEMM. wave owns ntiles 3w..3w+2 (of 36), all 4 mtiles ----
  {
    const int nt0 = wave * 3;
    const float bscale = (nt0 < 12) ? QKSCALE : 1.0f;  // q bias gets D^-0.5 too
    float bias[3];
#pragma unroll
    for (int n = 0; n < 3; ++n) bias[n] = qkv_b[(nt0 + n) * 16 + l15] * bscale;
    f32x4 acc[4][3];
#pragma unroll
    for (int m = 0; m < 4; ++m)
#pragma unroll
      for (int n = 0; n < 3; ++n) acc[m][n] = (f32x4){bias[n], bias[n], bias[n], bias[n]};
#pragma unroll
    for (int ks = 0; ks < 6; ++ks) {
      bf16x8 bf[3];
#pragma unroll
      for (int n = 0; n < 3; ++n)
        bf[n] = *reinterpret_cast<const bf16x8*>(wqkv + ((size_t)((nt0 + n) * 6 + ks) * 64 + lane) * 8);
#pragma unroll
      for (int m = 0; m < 4; ++m) {
        uint32_t row = (uint32_t)(m * 16 + l15);
        bf16x8 a = *reinterpret_cast<const bf16x8*>(smem + XOFF + row * 384u + swzA(row, (uint32_t)(ks * 64 + g16)));
#pragma unroll
        for (int n = 0; n < 3; ++n)
          acc[m][n] = __builtin_amdgcn_mfma_f32_16x16x32_bf16(a, bf[n], acc[m][n], 0, 0, 0);
      }
    }
    // scatter results to q/k/vT LDS. part is wave-uniform: waves 0-3 q, 4-7 k, 8-11 v.
    const int part = nt0 / 12;
    if (part == 2) {
      // v: tokens are the minor dim of vT -> 4 consecutive bf16 -> packed 8B writes
#pragma unroll
      for (int n = 0; n < 3; ++n) {
        int rem = (nt0 + n) - 24;
        int head = rem >> 1;
        int d = ((rem & 1) << 4) + l15;
        uint32_t rowbase = VOFF + (uint32_t)head * 6144u + (uint32_t)d * 128u;
#pragma unroll
        for (int m = 0; m < 4; ++m) {
          uint32_t c0 = (uint32_t)((m * 16 + rloc0) * 2);
          ushort4 hv = make_ushort4(f2bf(acc[m][n][0]), f2bf(acc[m][n][1]),
                                    f2bf(acc[m][n][2]), f2bf(acc[m][n][3]));
          *reinterpret_cast<ushort4*>(smem + rowbase + swzA((uint32_t)d, c0)) = hv;
        }
      }
    } else {
      const uint32_t base0 = (part == 0) ? QOFF : KOFF;
#pragma unroll
      for (int n = 0; n < 3; ++n) {
        int rem = (nt0 + n) % 12;
        int head = rem >> 1;
        int d = ((rem & 1) << 4) + l15;
#pragma unroll
        for (int m = 0; m < 4; ++m)
#pragma unroll
          for (int r = 0; r < 4; ++r) {
            uint32_t row = (uint32_t)(m * 16 + rloc0 + r);
            uint32_t addr = base0 + (uint32_t)head * 4096u + row * 64u + swzQ(row, (uint32_t)(d * 2));
            *reinterpret_cast<unsigned short*>(smem + addr) = f2bf(acc[m][n][r]);
          }
      }
    }
  }
  __syncthreads();

  // ---- Phase 3: attention. head = wave>>1, mtiles (wave&1)*2 + {0,1} ----
  {
    const int head = wave >> 1;
    const uint32_t pbase = POFF + (uint32_t)wave * 2048u;
    const uint32_t vbase = VOFF + (uint32_t)head * 6144u;
#pragma unroll
    for (int t = 0; t < 2; ++t) {
      const int mtile = ((wave & 1) << 1) + t;
      // bias (incl. -1e30 masking) preloaded straight into the MFMA accumulator
      const float* bt = bias_c + (size_t)((head * 4 + mtile) * 4 * 64 + lane) * 4;
      f32x4 s[4];
#pragma unroll
      for (int nt = 0; nt < 4; ++nt)
        s[nt] = *reinterpret_cast<const f32x4*>(bt + (size_t)nt * 256);
      uint32_t qrow = (uint32_t)(mtile * 16 + l15);
      bf16x8 qa = *reinterpret_cast<const bf16x8*>(smem + QOFF + (uint32_t)head * 4096u + qrow * 64u + swzQ(qrow, (uint32_t)g16));
#pragma unroll
      for (int nt = 0; nt < 4; ++nt) {
        uint32_t krow = (uint32_t)(nt * 16 + l15);
        bf16x8 kb = *reinterpret_cast<const bf16x8*>(smem + KOFF + (uint32_t)head * 4096u + krow * 64u + swzQ(krow, (uint32_t)g16));
        s[nt] = __builtin_amdgcn_mfma_f32_16x16x32_bf16(qa, kb, s[nt], 0, 0, 0);
      }
      // P = exp(S) (unnormalized; |S| small so no max-subtract; masked entries -> exp(-1e30)=0)
#pragma unroll
      for (int r = 0; r < 4; ++r) {
        int rl = rloc0 + r;
#pragma unroll
        for (int nt = 0; nt < 4; ++nt) {
          float e = __expf(s[nt][r]);
          uint32_t addr = pbase + (uint32_t)rl * 128u + swzA((uint32_t)rl, (uint32_t)((nt * 16 + l15) * 2));
          *reinterpret_cast<unsigned short*>(smem + addr) = f2bf(e);
        }
      }
      // PV: out[16][32] = P[16][64] @ V[64][32]; n2==2 tile's col 32 = row-sums of P (ones col)
      f32x4 o[3];
      o[0] = (f32x4){0.f, 0.f, 0.f, 0.f};
      o[1] = (f32x4){0.f, 0.f, 0.f, 0.f};
      o[2] = (f32x4){0.f, 0.f, 0.f, 0.f};
#pragma unroll
      for (int ks = 0; ks < 2; ++ks) {
        uint32_t prow = (uint32_t)l15;
        bf16x8 pa = *reinterpret_cast<const bf16x8*>(smem + pbase + prow * 128u + swzA(prow, (uint32_t)(ks * 64 + g16)));
#pragma unroll
        for (int n2 = 0; n2 < 3; ++n2) {
          uint32_t vrow = (uint32_t)(n2 * 16 + l15);
          bf16x8 vb = *reinterpret_cast<const bf16x8*>(smem + vbase + vrow * 128u + swzA(vrow, (uint32_t)(ks * 64 + g16)));
          o[n2] = __builtin_amdgcn_mfma_f32_16x16x32_bf16(pa, vb, o[n2], 0, 0, 0);
        }
      }
      // deferred softmax normalization: sum lives in o[2] at lane l15==0 of each group
#pragma unroll
      for (int r = 0; r < 4; ++r) {
        float sum = __shfl(o[2][r], lane & 48);
        float is = __builtin_amdgcn_rcpf(sum);
        int row = mtile * 16 + rloc0 + r;
#pragma unroll
        for (int n2 = 0; n2 < 2; ++n2) {
          int col = head * 32 + n2 * 16 + l15;
          uint32_t addr = AOFF + (uint32_t)row * 384u + swzA((uint32_t)row, (uint32_t)(col * 2));
          *reinterpret_cast<unsigned short*>(smem + addr) = f2bf(o[n2][r] * is);
        }
      }
    }
  }
  __syncthreads();

  // ---- Phase 4: proj. wave owns ntile=wave (cols 16w..16w+15), all 4 mtiles ----
  {
    const int ntp = wave;
    const float pb = proj_b[ntp * 16 + l15];
    f32x4 po[4];
#pragma unroll
    for (int m = 0; m < 4; ++m) po[m] = (f32x4){pb, pb, pb, pb};
#pragma unroll
    for (int ks = 0; ks < 6; ++ks) {
      bf16x8 bfp = *reinterpret_cast<const bf16x8*>(wproj + ((size_t)(ntp * 6 + ks) * 64 + lane) * 8);
#pragma unroll
      for (int m = 0; m < 4; ++m) {
        uint32_t row = (uint32_t)(m * 16 + l15);
        bf16x8 a = *reinterpret_cast<const bf16x8*>(smem + AOFF + row * 384u + swzA(row, (uint32_t)(ks * 64 + g16)));
        po[m] = __builtin_amdgcn_mfma_f32_16x16x32_bf16(a, bfp, po[m], 0, 0, 0);
      }
    }
    float* outg = out + (size_t)b * (TOK * CDIM);
    const int col = ntp * 16 + l15;
#pragma unroll
    for (int m = 0; m < 4; ++m)
#pragma unroll
      for (int r = 0; r < 4; ++r) {
        int row = m * 16 + rloc0 + r;
        if (row < TOK) outg[row * CDIM + col] = po[m][r];
      }
  }
}

extern "C" void kernel_launch(void* const* d_in, const int* in_sizes, int n_in,
                              void* d_out, int out_size, void* d_ws, size_t ws_size,
                              hipStream_t stream) {
  const float* x = (const float*)d_in[0];
  // d_in[1] = q_global : unused by the reference
  const float* qkv_w = (const float*)d_in[2];
  const float* qkv_b = (const float*)d_in[3];
  const float* proj_w = (const float*)d_in[4];
  const float* proj_b = (const float*)d_in[5];
  const float* rpb = (const float*)d_in[6];

  unsigned short* wqkv = (unsigned short*)d_ws;                 // 36*6*64*8 bf16 = 221184 B
  unsigned short* wproj = wqkv + (size_t)36 * 6 * 64 * 8;       // 12*6*64*8 bf16 = 73728 B
  float* bias_c = (float*)(wproj + (size_t)12 * 6 * 64 * 8);    // 6*4*4*64*4 f32 = 98304 B

  wa_pack_w<<<(36 * 6 * 64 + 255) / 256, 256, 0, stream>>>(qkv_w, wqkv, 36, 576, 12, QKSCALE);
  wa_pack_w<<<(12 * 6 * 64 + 255) / 256, 256, 0, stream>>>(proj_w, wproj, 12, 192, 0, 1.0f);
  wa_pack_bias<<<(NHEAD * 4 * 4 * 64 + 255) / 256, 256, 0, stream>>>(rpb, bias_c);

  hipFuncSetAttribute((const void*)wa_main, hipFuncAttributeMaxDynamicSharedMemorySize, (int)SMEM_BYTES);
  wa_main<<<2048, THREADS, SMEM_BYTES, stream>>>(x, qkv_b, proj_b, bias_c, wqkv, wproj, (float*)d_out);
}